// Round 8
// baseline (58.283 us; speedup 1.0000x reference)
//
#include <hip/hip_runtime.h>

namespace {
constexpr int kT   = 336;
constexpr int kC   = 512;
constexpr int kK   = 3;
constexpr int kR   = 8;           // rows per chunk; 336 = 42 * 8
constexpr int kNB  = 5;           // LDS ring depth (prefetch 4 ahead)
}

// One wave per block (64 threads), one thread per (b,c); 2048 blocks -> work
// distributes at wave granularity (R7's 4-wave blocks left CUs half-idle in
// the tail). x staged into a 5-buffer LDS ring via 16B global_load_lds
// (2 instrs / 8-row chunk). Counted vmcnt per phase (2 loads + 8 stores):
//   prologue 6/14/22/30, steady 38 (retires L_k; L_{k+1..k+3} + stores with
//   >=5 phases of ack slack stay in flight), tail 38/36/34/32.
// Single wave -> no __syncthreads anywhere; no barrier drain exists.
#define WAITV(n) do { asm volatile("s_waitcnt vmcnt(" #n ")" ::: "memory"); \
                      __builtin_amdgcn_sched_barrier(0); } while (0)

__global__ __launch_bounds__(64) void ema_mix_kernel(
    const float* __restrict__ x,
    const float* __restrict__ logit_alpha,
    const float* __restrict__ mix_logits,
    float* __restrict__ out)
{
    __shared__ float buf[kNB][kR][64];   // 10 KB

    const int lane = threadIdx.x;             // 0..63, single wave
    const int c0   = (blockIdx.x & 7) << 6;
    const int b    = blockIdx.x >> 3;
    const int c    = c0 + lane;

    // ---- per-(k,c) parameters ----
    float a[kK], oma[kK], inva[kK], mixw[kK];
    {
        float logits[kK];
        float lmax = -3.402823e38f;
        #pragma unroll
        for (int k = 0; k < kK; ++k) {
            logits[k] = mix_logits[c * kK + k];
            lmax = fmaxf(lmax, logits[k]);
        }
        float esum = 0.f;
        #pragma unroll
        for (int k = 0; k < kK; ++k) {
            logits[k] = expf(logits[k] - lmax);
            esum += logits[k];
        }
        const float rs = 1.0f / esum;
        #pragma unroll
        for (int k = 0; k < kK; ++k) {
            mixw[k] = logits[k] * rs;
            const float z = logit_alpha[k * kC + c];
            float s;
            if (z >= 0.f) {
                s = 1.0f / (1.0f + expf(-z));
            } else {
                const float e = expf(z);
                s = e / (1.0f + e);
            }
            s = fminf(fmaxf(s, 1e-4f), (float)(1.0 - 1e-4));
            a[k]    = s;
            oma[k]  = 1.0f - s;
            inva[k] = 1.0f / s;
        }
    }

    // drain param loads so the vmcnt queue is empty at pipeline start
    asm volatile("s_waitcnt vmcnt(0)" ::: "memory");
    __builtin_amdgcn_sched_barrier(0);

    const float* xbase = x + (size_t)b * (kT * kC);
    float*       op    = out + (size_t)b * (kT * kC) + c;

    // staging lane mapping (16B-wide global_load_lds): lane>>4 = row in
    // 4-row group, (lane&15)*4 = col quad; LDS dest = base + lane*16.
    const int roff = lane >> 4;
    const int scol = c0 + ((lane & 15) << 2);

    float apow[kK], vinv[kK], S[kK];
    #pragma unroll
    for (int k = 0; k < kK; ++k) { apow[k] = 1.f; vinv[k] = 1.f; S[k] = 0.f; }

    auto stage = [&](int ch, int bi) {
        #pragma unroll
        for (int q = 0; q < 2; ++q) {
            const float* g = xbase + ((size_t)(ch * kR + q * 4 + roff) * kC + scol);
            __builtin_amdgcn_global_load_lds(
                (const __attribute__((address_space(1))) void*)g,
                (__attribute__((address_space(3))) void*)(&buf[bi][q * 4][0]),
                16, 0, 0);
        }
    };

    auto compute = [&](int ch, int bi, bool first) {
        const int tbase = ch * kR;
        #pragma unroll
        for (int i = 0; i < kR; ++i) {
            const float xv = buf[bi][i][lane];   // ds_read_b32, 2-way = free
            float o = 0.f;
            #pragma unroll
            for (int k = 0; k < kK; ++k) {
                const float wt = (first && i == 0) ? 1.0f : apow[k] * oma[k];
                S[k] = fmaf(xv, wt, S[k]);
                o = fmaf(S[k] * mixw[k], fminf(vinv[k], 1e8f), o);
                apow[k] *= a[k];
                vinv[k] *= inva[k];
            }
            __builtin_nontemporal_store(o, &op[(size_t)(tbase + i) * kC]);
        }
    };

    // ---- prologue: 4 chunks in flight (8 loads) ----
    stage(0, 0); stage(1, 1); stage(2, 2); stage(3, 3);

    // phase k: WAITV(n_k) retires L_k; n_k = ops issued after L_k.
    WAITV( 6); stage(4, 4); compute(0, 0, true);
    WAITV(14); stage(5, 0); compute(1, 1, false);
    WAITV(22); stage(6, 1); compute(2, 2, false);
    WAITV(30); stage(7, 2); compute(3, 3, false);

    int cb = 4, sb = 3;   // buf of chunk k (k%5) and of chunk k+4 ((k+4)%5)
    #pragma unroll 1
    for (int k = 4; k <= 37; ++k) {
        WAITV(38);                    // newer than L_k: 3L + 4S groups = 38
        stage(k + 4, sb);
        compute(k, cb, false);
        cb = (cb + 1 == kNB) ? 0 : cb + 1;
        sb = (sb + 1 == kNB) ? 0 : sb + 1;
    }

    // tail: chunks 38..41 (no more staging; load tail drains)
    WAITV(38); compute(38, 3, false);
    WAITV(36); compute(39, 4, false);
    WAITV(34); compute(40, 0, false);
    WAITV(32); compute(41, 1, false);
}

extern "C" void kernel_launch(void* const* d_in, const int* in_sizes, int n_in,
                              void* d_out, int out_size, void* d_ws, size_t ws_size,
                              hipStream_t stream) {
    const float* x  = (const float*)d_in[0];
    const float* la = (const float*)d_in[1];
    const float* ml = (const float*)d_in[2];
    float* o = (float*)d_out;

    const int blocks = 256 * (kC / 64);   // 2048 one-wave blocks
    ema_mix_kernel<<<dim3(blocks), dim3(64), 0, stream>>>(x, la, ml, o);
}